// Round 6
// baseline (1039.407 us; speedup 1.0000x reference)
//
#include <hip/hip_runtime.h>
#include <hip/hip_bf16.h>

#define BK   128      // nodes per bucket
#define NBMAX 2048    // max buckets (N<=262144)

__device__ __forceinline__ float uaf(unsigned u) { return __uint_as_float(u); }

// ---------------- bucket-grouped edge staging ----------------

// count edges per bucket (bucket = dst >> 7)
__global__ void __launch_bounds__(256) k_bcount(const int* dst, int* bcnt, int E, int NB) {
    __shared__ int h[NBMAX];
    for (int i = threadIdx.x; i < NB; i += 256) h[i] = 0;
    __syncthreads();
    int stride = gridDim.x * 256;
    for (int e = blockIdx.x * 256 + threadIdx.x; e < E; e += stride)
        atomicAdd(&h[dst[e] >> 7], 1);
    __syncthreads();
    for (int i = threadIdx.x; i < NB; i += 256) {
        int v = h[i];
        if (v) atomicAdd(&bcnt[i], v);
    }
}

// exclusive scan of bucket counts (single block)
__global__ void __launch_bounds__(256) k_bscan(const int* bcnt, int* boff, int* bcur, int NB, int E) {
    __shared__ int lds[256];
    __shared__ int carry;
    int t = threadIdx.x;
    if (t == 0) carry = 0;
    __syncthreads();
    for (int base = 0; base < NB; base += 256) {
        int v = (base + t < NB) ? bcnt[base + t] : 0;
        lds[t] = v;
        __syncthreads();
        for (int o = 1; o < 256; o <<= 1) {
            int u = (t >= o) ? lds[t - o] : 0;
            __syncthreads();
            lds[t] += u;
            __syncthreads();
        }
        int excl = lds[t] - v + carry;
        if (base + t < NB) { boff[base + t] = excl; bcur[base + t] = excl; }
        __syncthreads();
        if (t == 0) carry += lds[255];
        __syncthreads();
    }
    if (t == 0) boff[NB] = E;
}

// scatter packed (src<<7 | dst&127) into bucket-grouped staging.
#define EPB 16384
__global__ void __launch_bounds__(256) k_bscatter(const int* ei, int* bcur,
                                                  unsigned* stag, int E, int NB) {
    __shared__ int lhist[NBMAX];
    __shared__ int lbase[NBMAX];
    int t = threadIdx.x;
    for (int i = t; i < NB; i += 256) lhist[i] = 0;
    __syncthreads();
    int base = blockIdx.x * EPB;
    int lim = min(EPB, E - base);
    for (int c = t; c < lim; c += 256)
        atomicAdd(&lhist[ei[E + base + c] >> 7], 1);
    __syncthreads();
    for (int i = t; i < NB; i += 256) {
        int v = lhist[i];
        lbase[i] = v ? atomicAdd(&bcur[i], v) : 0;
    }
    __syncthreads();
    for (int c = t; c < lim; c += 256) {
        int s = ei[base + c];
        int d = ei[E + base + c];
        int p = atomicAdd(&lbase[d >> 7], 1);
        stag[p] = ((unsigned)s << 7) | (unsigned)(d & (BK - 1));
    }
}

// per-bucket counting sort: stag (bucket-grouped) -> csr (node-grouped).
// Also emits per-node offs, dis, dx.
__global__ void __launch_bounds__(256) k_sort(const int* boff, const unsigned* stag,
                                              const float* x, int* csr, int* offs,
                                              float* dis, float* dx, int N, int NB) {
    __shared__ int cnt[BK];
    __shared__ int sc[BK];
    __shared__ int base[BK];
    int t = threadIdx.x, bu = blockIdx.x;
    if (t < BK) cnt[t] = 0;
    __syncthreads();
    int lo = boff[bu], hi = boff[bu + 1];
    for (int k = lo + t; k < hi; k += 256)
        atomicAdd(&cnt[stag[k] & (BK - 1)], 1);
    __syncthreads();
    if (t < BK) sc[t] = cnt[t];
    __syncthreads();
    for (int o = 1; o < BK; o <<= 1) {
        int v = (t < BK && t >= o) ? sc[t - o] : 0;
        __syncthreads();
        if (t < BK) sc[t] += v;
        __syncthreads();
    }
    int excl = (t < BK) ? sc[t] - cnt[t] : 0;
    if (t < BK) base[t] = excl;
    int node = bu * BK + t;
    if (t < BK && node < N) {
        offs[node] = lo + excl;
        float d = rsqrtf((float)(cnt[t] + 1));   // +1 self-loop
        dis[node] = d;
        dx[node]  = d * x[node];
    }
    if (bu == NB - 1 && t == 0) offs[N] = hi;
    __syncthreads();
    for (int k = lo + t; k < hi; k += 256) {
        unsigned en = stag[k];
        int p = atomicAdd(&base[en & (BK - 1)], 1);
        csr[lo + p] = (int)(en >> 7);
    }
}

// layer-1 scalar aggregation: thread per node on sorted CSR (self-loop analytic)
__global__ void k_agg1(const int* offs, const int* csr, const float* dx,
                       const float* dis, float* s1, int N) {
    int i = blockIdx.x * blockDim.x + threadIdx.x;
    if (i >= N) return;
    int b = offs[i], e = offs[i + 1];
    float acc = 0.f;
    int k = b;
    for (; k + 8 <= e; k += 8) {
        int s0 = csr[k], s1_ = csr[k + 1], s2 = csr[k + 2], s3 = csr[k + 3];
        int s4 = csr[k + 4], s5 = csr[k + 5], s6 = csr[k + 6], s7 = csr[k + 7];
        float v0 = dx[s0], v1 = dx[s1_], v2 = dx[s2], v3 = dx[s3];
        float v4 = dx[s4], v5 = dx[s5], v6 = dx[s6], v7 = dx[s7];
        acc += ((v0 + v1) + (v2 + v3)) + ((v4 + v5) + (v6 + v7));
    }
    for (; k < e; ++k) acc += dx[csr[k]];
    s1[i] = dis[i] * (acc + dx[i]);
}

// hw1b[i] = bf16( dis[i] * (relu(s1[i]*Wg1 + bg1) @ Wg2) ), Wg2 in LDS
__global__ void __launch_bounds__(256) k_hw1(const float* s1, const float* dis,
                                             const float* Wg1, const float* bg1,
                                             const float* Wg2,
                                             __hip_bfloat16* hw1b, int N) {
    __shared__ float w2[64 * 64];
    __shared__ float h1l[4][64];
    int t = threadIdx.x;
    for (int k = t; k < 64 * 64; k += 256) w2[k] = Wg2[k];
    int nl = t >> 6, l = t & 63;
    int base = blockIdx.x * 16;
    for (int g = 0; g < 4; ++g) {
        int node = base + g * 4 + nl;
        float h1 = 0.f;
        if (node < N)
            h1 = fmaxf(fmaf(s1[node], Wg1[l], bg1[l]), 0.f);
        __syncthreads();
        h1l[nl][l] = h1;
        __syncthreads();
        if (node < N) {
            float acc = 0.f;
            const float* hr = h1l[nl];
            #pragma unroll
            for (int k = 0; k < 64; ++k) acc += hr[k] * w2[k * 64 + l];
            hw1b[node * 64 + l] = __float2bfloat16(dis[node] * acc);
        }
    }
}

// layer-2 aggregation v2: wave per dst node; 8 edge-slots x 8 feature-chunks.
// Lane l: edge k+(l>>3), features (l&7)*8..+7 via one uint4 (16B = 8 bf16).
// One vmem instr covers 8 rows (16 lines); x2 manual unroll = 32 lines in flight.
__global__ void __launch_bounds__(256) k_agg2(const int* offs, const int* csr,
                                              const __hip_bfloat16* hw1b,
                                              const float* dis, const float* bg2,
                                              const int* batch, float* pool, int N) {
    int i = (blockIdx.x * 256 + threadIdx.x) >> 6;  // node = global wave id
    if (i >= N) return;
    int l = threadIdx.x & 63;
    int slot = l >> 3;          // which of 8 edges
    int c    = l & 7;           // feature chunk: features c*8 .. c*8+7
    int b = offs[i], e = offs[i + 1];
    float acc[8] = {0.f, 0.f, 0.f, 0.f, 0.f, 0.f, 0.f, 0.f};
    int k = b;
    // main loop: 16 edges per iteration, unmasked
    for (; k + 16 <= e; k += 16) {
        int srcA = csr[k + slot];
        int srcB = csr[k + 8 + slot];
        uint4 uA = *(const uint4*)(hw1b + (size_t)srcA * 64 + c * 8);
        uint4 uB = *(const uint4*)(hw1b + (size_t)srcB * 64 + c * 8);
        acc[0] += uaf(uA.x << 16);          acc[0] += uaf(uB.x << 16);
        acc[1] += uaf(uA.x & 0xffff0000u);  acc[1] += uaf(uB.x & 0xffff0000u);
        acc[2] += uaf(uA.y << 16);          acc[2] += uaf(uB.y << 16);
        acc[3] += uaf(uA.y & 0xffff0000u);  acc[3] += uaf(uB.y & 0xffff0000u);
        acc[4] += uaf(uA.z << 16);          acc[4] += uaf(uB.z << 16);
        acc[5] += uaf(uA.z & 0xffff0000u);  acc[5] += uaf(uB.z & 0xffff0000u);
        acc[6] += uaf(uA.w << 16);          acc[6] += uaf(uB.w << 16);
        acc[7] += uaf(uA.w & 0xffff0000u);  acc[7] += uaf(uB.w & 0xffff0000u);
    }
    // tail: masked 8-edge steps
    for (; k < e; k += 8) {
        int idx = k + slot;
        bool v = idx < e;
        int src = csr[v ? idx : (e - 1)];
        uint4 u = *(const uint4*)(hw1b + (size_t)src * 64 + c * 8);
        float m = v ? 1.f : 0.f;
        acc[0] = fmaf(m, uaf(u.x << 16),         acc[0]);
        acc[1] = fmaf(m, uaf(u.x & 0xffff0000u), acc[1]);
        acc[2] = fmaf(m, uaf(u.y << 16),         acc[2]);
        acc[3] = fmaf(m, uaf(u.y & 0xffff0000u), acc[3]);
        acc[4] = fmaf(m, uaf(u.z << 16),         acc[4]);
        acc[5] = fmaf(m, uaf(u.z & 0xffff0000u), acc[5]);
        acc[6] = fmaf(m, uaf(u.w << 16),         acc[6]);
        acc[7] = fmaf(m, uaf(u.w & 0xffff0000u), acc[7]);
    }
    // butterfly reduce across the 8 edge-slots (lanes l, l^8, l^16, l^32)
    #pragma unroll
    for (int j = 0; j < 8; ++j) {
        acc[j] += __shfl_xor(acc[j], 8, 64);
        acc[j] += __shfl_xor(acc[j], 16, 64);
        acc[j] += __shfl_xor(acc[j], 32, 64);
    }
    // finalize on slot-0 lanes: self-loop + relu + pool
    if (slot == 0) {
        float di = dis[i];
        int g = batch[i];
        uint4 su = *(const uint4*)(hw1b + (size_t)i * 64 + c * 8);
        float s0 = uaf(su.x << 16), s1 = uaf(su.x & 0xffff0000u);
        float s2 = uaf(su.y << 16), s3 = uaf(su.y & 0xffff0000u);
        float s4 = uaf(su.z << 16), s5 = uaf(su.z & 0xffff0000u);
        float s6 = uaf(su.w << 16), s7 = uaf(su.w & 0xffff0000u);
        float* pg = pool + (size_t)g * 64 + c * 8;
        const float* bg = bg2 + c * 8;
        float h;
        h = fmaxf(fmaf(di, acc[0] + s0, bg[0]), 0.f); atomicAdd(pg + 0, h);
        h = fmaxf(fmaf(di, acc[1] + s1, bg[1]), 0.f); atomicAdd(pg + 1, h);
        h = fmaxf(fmaf(di, acc[2] + s2, bg[2]), 0.f); atomicAdd(pg + 2, h);
        h = fmaxf(fmaf(di, acc[3] + s3, bg[3]), 0.f); atomicAdd(pg + 3, h);
        h = fmaxf(fmaf(di, acc[4] + s4, bg[4]), 0.f); atomicAdd(pg + 4, h);
        h = fmaxf(fmaf(di, acc[5] + s5, bg[5]), 0.f); atomicAdd(pg + 5, h);
        h = fmaxf(fmaf(di, acc[6] + s6, bg[6]), 0.f); atomicAdd(pg + 6, h);
        h = fmaxf(fmaf(di, acc[7] + s7, bg[7]), 0.f); atomicAdd(pg + 7, h);
    }
}

// per-graph head: tabular MLP + mean pool + fusion MLP. 64 threads per graph.
__global__ void __launch_bounds__(64) k_head(const float* tabular,
        const float* Wt1, const float* bt1, const float* Wt2, const float* bt2,
        const float* Wf1, const float* bf1, const float* Wf2, const float* bf2,
        const float* pool, const int* batch, float* out, int TD, int N) {
    __shared__ float tl[128];
    __shared__ float t1[64];
    __shared__ float comb[128];
    __shared__ float f1[64];
    __shared__ float cnts;
    int g = blockIdx.x, l = threadIdx.x;
    if (l == 0) {
        int lo = 0, hi = N;
        while (lo < hi) { int m = (lo + hi) >> 1; if (batch[m] < g) lo = m + 1; else hi = m; }
        int lo2 = lo, hi2 = N;
        while (lo2 < hi2) { int m = (lo2 + hi2) >> 1; if (batch[m] <= g) lo2 = m + 1; else hi2 = m; }
        int c = lo2 - lo;
        cnts = (float)(c > 1 ? c : 1);
    }
    for (int k = l; k < TD; k += 64) tl[k] = tabular[g * TD + k];
    __syncthreads();
    float a = bt1[l];
    for (int k = 0; k < TD; ++k) a += tl[k] * Wt1[k * 64 + l];
    t1[l] = a > 0.f ? a : 0.f;
    __syncthreads();
    float b = bt2[l];
    #pragma unroll
    for (int k = 0; k < 64; ++k) b += t1[k] * Wt2[k * 64 + l];
    comb[l] = b;
    comb[64 + l] = pool[g * 64 + l] / cnts;
    __syncthreads();
    float f = bf1[l];
    for (int k = 0; k < 128; ++k) f += comb[k] * Wf1[k * 64 + l];
    f1[l] = f > 0.f ? f : 0.f;
    __syncthreads();
    if (l < 2) {
        float o = bf2[l];
        #pragma unroll
        for (int k = 0; k < 64; ++k) o += f1[k] * Wf2[k * 2 + l];
        out[g * 2 + l] = o;
    }
}

// ---------------- launcher ----------------

extern "C" void kernel_launch(void* const* d_in, const int* in_sizes, int n_in,
                              void* d_out, int out_size, void* d_ws, size_t ws_size,
                              hipStream_t stream) {
    const float* tabular = (const float*)d_in[0];
    const float* x       = (const float*)d_in[1];
    const int*   ei      = (const int*)d_in[2];
    const int*   batch   = (const int*)d_in[3];
    const float* Wt1 = (const float*)d_in[4];
    const float* bt1 = (const float*)d_in[5];
    const float* Wt2 = (const float*)d_in[6];
    const float* bt2 = (const float*)d_in[7];
    const float* Wg1 = (const float*)d_in[8];
    const float* bg1 = (const float*)d_in[9];
    const float* Wg2 = (const float*)d_in[10];
    const float* bg2 = (const float*)d_in[11];
    const float* Wf1 = (const float*)d_in[12];
    const float* bf1 = (const float*)d_in[13];
    const float* Wf2 = (const float*)d_in[14];
    const float* bf2 = (const float*)d_in[15];

    const int N  = in_sizes[1];
    const int E  = in_sizes[2] / 2;
    const int H  = in_sizes[5];             // 64
    const int TD = in_sizes[4] / H;         // 128
    const int B  = in_sizes[0] / TD;        // 1024
    const int NB = (N + BK - 1) / BK;       // 1563

    // workspace layout
    char* w = (char*)d_ws;
    size_t off = 0;
    auto alloc = [&](size_t bytes) -> void* {
        void* p = w + off;
        off = (off + bytes + 255) & ~(size_t)255;
        return p;
    };
    int*   bcnt = (int*)alloc((size_t)NBMAX * 4);
    int*   boff = (int*)alloc((size_t)(NBMAX + 1) * 4);
    int*   bcur = (int*)alloc((size_t)NBMAX * 4);
    int*   offs = (int*)alloc((size_t)(N + 1) * 4);
    float* dis  = (float*)alloc((size_t)N * 4);
    float* dx   = (float*)alloc((size_t)N * 4);
    float* s1   = (float*)alloc((size_t)N * 4);
    unsigned* stag = (unsigned*)alloc((size_t)E * 4);
    int*   csr  = (int*)alloc((size_t)E * 4);
    __hip_bfloat16* hw1b = (__hip_bfloat16*)alloc((size_t)N * 64 * 2);
    float* pool = (float*)alloc((size_t)B * 64 * 4);
    (void)ws_size;

    hipMemsetAsync(bcnt, 0, (size_t)NB * 4, stream);
    hipMemsetAsync(pool, 0, (size_t)B * 64 * 4, stream);

    k_bcount<<<512, 256, 0, stream>>>(ei + E, bcnt, E, NB);
    k_bscan<<<1, 256, 0, stream>>>(bcnt, boff, bcur, NB, E);
    k_bscatter<<<(E + EPB - 1) / EPB, 256, 0, stream>>>(ei, bcur, stag, E, NB);
    k_sort<<<NB, 256, 0, stream>>>(boff, stag, x, csr, offs, dis, dx, N, NB);
    k_agg1<<<(N + 255) / 256, 256, 0, stream>>>(offs, csr, dx, dis, s1, N);
    k_hw1<<<(N + 15) / 16, 256, 0, stream>>>(s1, dis, Wg1, bg1, Wg2, hw1b, N);
    k_agg2<<<(N + 3) / 4, 256, 0, stream>>>(offs, csr, hw1b, dis, bg2, batch, pool, N);
    k_head<<<B, 64, 0, stream>>>(tabular, Wt1, bt1, Wt2, bt2,
                                 Wf1, bf1, Wf2, bf2, pool, batch,
                                 (float*)d_out, TD, N);
}

// Round 7
// 584.910 us; speedup vs baseline: 1.7770x; 1.7770x over previous
//
#include <hip/hip_runtime.h>
#include <hip/hip_bf16.h>

#define BK   128      // nodes per bucket
#define NBMAX 2048    // max buckets (N<=262144)

__device__ __forceinline__ float uaf(unsigned u) { return __uint_as_float(u); }

__device__ __forceinline__ void acc8(float* acc, uint4 u) {
    acc[0] += uaf(u.x << 16); acc[1] += uaf(u.x & 0xffff0000u);
    acc[2] += uaf(u.y << 16); acc[3] += uaf(u.y & 0xffff0000u);
    acc[4] += uaf(u.z << 16); acc[5] += uaf(u.z & 0xffff0000u);
    acc[6] += uaf(u.w << 16); acc[7] += uaf(u.w & 0xffff0000u);
}

// ---------------- bucket-grouped edge staging ----------------

// count edges per bucket (bucket = dst >> 7)
__global__ void __launch_bounds__(256) k_bcount(const int* dst, int* bcnt, int E, int NB) {
    __shared__ int h[NBMAX];
    for (int i = threadIdx.x; i < NB; i += 256) h[i] = 0;
    __syncthreads();
    int stride = gridDim.x * 256;
    for (int e = blockIdx.x * 256 + threadIdx.x; e < E; e += stride)
        atomicAdd(&h[dst[e] >> 7], 1);
    __syncthreads();
    for (int i = threadIdx.x; i < NB; i += 256) {
        int v = h[i];
        if (v) atomicAdd(&bcnt[i], v);
    }
}

// exclusive scan of bucket counts (single block)
__global__ void __launch_bounds__(256) k_bscan(const int* bcnt, int* boff, int* bcur, int NB, int E) {
    __shared__ int lds[256];
    __shared__ int carry;
    int t = threadIdx.x;
    if (t == 0) carry = 0;
    __syncthreads();
    for (int base = 0; base < NB; base += 256) {
        int v = (base + t < NB) ? bcnt[base + t] : 0;
        lds[t] = v;
        __syncthreads();
        for (int o = 1; o < 256; o <<= 1) {
            int u = (t >= o) ? lds[t - o] : 0;
            __syncthreads();
            lds[t] += u;
            __syncthreads();
        }
        int excl = lds[t] - v + carry;
        if (base + t < NB) { boff[base + t] = excl; bcur[base + t] = excl; }
        __syncthreads();
        if (t == 0) carry += lds[255];
        __syncthreads();
    }
    if (t == 0) boff[NB] = E;
}

// scatter packed (src<<7 | dst&127) into bucket-grouped staging.
#define EPB 16384
__global__ void __launch_bounds__(256) k_bscatter(const int* ei, int* bcur,
                                                  unsigned* stag, int E, int NB) {
    __shared__ int lhist[NBMAX];
    __shared__ int lbase[NBMAX];
    int t = threadIdx.x;
    for (int i = t; i < NB; i += 256) lhist[i] = 0;
    __syncthreads();
    int base = blockIdx.x * EPB;
    int lim = min(EPB, E - base);
    for (int c = t; c < lim; c += 256)
        atomicAdd(&lhist[ei[E + base + c] >> 7], 1);
    __syncthreads();
    for (int i = t; i < NB; i += 256) {
        int v = lhist[i];
        lbase[i] = v ? atomicAdd(&bcur[i], v) : 0;
    }
    __syncthreads();
    for (int c = t; c < lim; c += 256) {
        int s = ei[base + c];
        int d = ei[E + base + c];
        int p = atomicAdd(&lbase[d >> 7], 1);
        stag[p] = ((unsigned)s << 7) | (unsigned)(d & (BK - 1));
    }
}

// per-bucket counting sort: stag (bucket-grouped) -> csr (node-grouped).
// Also emits per-node offs, dis, dx.
__global__ void __launch_bounds__(256) k_sort(const int* boff, const unsigned* stag,
                                              const float* x, int* csr, int* offs,
                                              float* dis, float* dx, int N, int NB) {
    __shared__ int cnt[BK];
    __shared__ int sc[BK];
    __shared__ int base[BK];
    int t = threadIdx.x, bu = blockIdx.x;
    if (t < BK) cnt[t] = 0;
    __syncthreads();
    int lo = boff[bu], hi = boff[bu + 1];
    for (int k = lo + t; k < hi; k += 256)
        atomicAdd(&cnt[stag[k] & (BK - 1)], 1);
    __syncthreads();
    if (t < BK) sc[t] = cnt[t];
    __syncthreads();
    for (int o = 1; o < BK; o <<= 1) {
        int v = (t < BK && t >= o) ? sc[t - o] : 0;
        __syncthreads();
        if (t < BK) sc[t] += v;
        __syncthreads();
    }
    int excl = (t < BK) ? sc[t] - cnt[t] : 0;
    if (t < BK) base[t] = excl;
    int node = bu * BK + t;
    if (t < BK && node < N) {
        offs[node] = lo + excl;
        float d = rsqrtf((float)(cnt[t] + 1));   // +1 self-loop
        dis[node] = d;
        dx[node]  = d * x[node];
    }
    if (bu == NB - 1 && t == 0) offs[N] = hi;
    __syncthreads();
    for (int k = lo + t; k < hi; k += 256) {
        unsigned en = stag[k];
        int p = atomicAdd(&base[en & (BK - 1)], 1);
        csr[lo + p] = (int)(en >> 7);
    }
}

// layer-1 scalar aggregation: thread per node on sorted CSR (self-loop analytic)
__global__ void k_agg1(const int* offs, const int* csr, const float* dx,
                       const float* dis, float* s1, int N) {
    int i = blockIdx.x * blockDim.x + threadIdx.x;
    if (i >= N) return;
    int b = offs[i], e = offs[i + 1];
    float acc = 0.f;
    int k = b;
    for (; k + 8 <= e; k += 8) {
        int s0 = csr[k], s1_ = csr[k + 1], s2 = csr[k + 2], s3 = csr[k + 3];
        int s4 = csr[k + 4], s5 = csr[k + 5], s6 = csr[k + 6], s7 = csr[k + 7];
        float v0 = dx[s0], v1 = dx[s1_], v2 = dx[s2], v3 = dx[s3];
        float v4 = dx[s4], v5 = dx[s5], v6 = dx[s6], v7 = dx[s7];
        acc += ((v0 + v1) + (v2 + v3)) + ((v4 + v5) + (v6 + v7));
    }
    for (; k < e; ++k) acc += dx[csr[k]];
    s1[i] = dis[i] * (acc + dx[i]);
}

// hw1b[i] = bf16( dis[i] * (relu(s1[i]*Wg1 + bg1) @ Wg2) ), Wg2 in LDS
__global__ void __launch_bounds__(256) k_hw1(const float* s1, const float* dis,
                                             const float* Wg1, const float* bg1,
                                             const float* Wg2,
                                             __hip_bfloat16* hw1b, int N) {
    __shared__ float w2[64 * 64];
    __shared__ float h1l[4][64];
    int t = threadIdx.x;
    for (int k = t; k < 64 * 64; k += 256) w2[k] = Wg2[k];
    int nl = t >> 6, l = t & 63;
    int base = blockIdx.x * 16;
    for (int g = 0; g < 4; ++g) {
        int node = base + g * 4 + nl;
        float h1 = 0.f;
        if (node < N)
            h1 = fmaxf(fmaf(s1[node], Wg1[l], bg1[l]), 0.f);
        __syncthreads();
        h1l[nl][l] = h1;
        __syncthreads();
        if (node < N) {
            float acc = 0.f;
            const float* hr = h1l[nl];
            #pragma unroll
            for (int k = 0; k < 64; ++k) acc += hr[k] * w2[k * 64 + l];
            hw1b[node * 64 + l] = __float2bfloat16(dis[node] * acc);
        }
    }
}

// layer-2 aggregation v3: wave per dst node; 8 edge-slots x 8 feature-chunks.
// Lane l: edge k+(l>>3), features (l&7)*8..+7 via one uint4 (16B = 8 bf16).
// 4x unrolled = 64 lines in flight per wave. Finalize: butterfly over slots,
// 8-shuffle transpose back to lane=feature, ONE coalesced 64-lane atomic.
__global__ void __launch_bounds__(256) k_agg2(const int* offs, const int* csr,
                                              const __hip_bfloat16* hw1b,
                                              const float* dis, const float* bg2,
                                              const int* batch, float* pool, int N) {
    int i = (blockIdx.x * 256 + threadIdx.x) >> 6;  // node = global wave id
    if (i >= N) return;
    int l = threadIdx.x & 63;
    int slot = l >> 3;          // which of 8 edges
    int c    = l & 7;           // feature chunk: features c*8 .. c*8+7
    int b = offs[i], e = offs[i + 1];
    float acc[8] = {0.f, 0.f, 0.f, 0.f, 0.f, 0.f, 0.f, 0.f};
    int k = b;
    for (; k + 32 <= e; k += 32) {
        int sA = csr[k + slot];
        int sB = csr[k + 8 + slot];
        int sC = csr[k + 16 + slot];
        int sD = csr[k + 24 + slot];
        uint4 uA = *(const uint4*)(hw1b + (size_t)sA * 64 + c * 8);
        uint4 uB = *(const uint4*)(hw1b + (size_t)sB * 64 + c * 8);
        uint4 uC = *(const uint4*)(hw1b + (size_t)sC * 64 + c * 8);
        uint4 uD = *(const uint4*)(hw1b + (size_t)sD * 64 + c * 8);
        acc8(acc, uA); acc8(acc, uB); acc8(acc, uC); acc8(acc, uD);
    }
    for (; k + 16 <= e; k += 16) {
        int sA = csr[k + slot];
        int sB = csr[k + 8 + slot];
        uint4 uA = *(const uint4*)(hw1b + (size_t)sA * 64 + c * 8);
        uint4 uB = *(const uint4*)(hw1b + (size_t)sB * 64 + c * 8);
        acc8(acc, uA); acc8(acc, uB);
    }
    for (; k + 8 <= e; k += 8) {
        int sA = csr[k + slot];
        uint4 uA = *(const uint4*)(hw1b + (size_t)sA * 64 + c * 8);
        acc8(acc, uA);
    }
    if (k < e) {   // masked tail, <8 edges
        int idx = k + slot;
        bool v = idx < e;
        int src = v ? csr[idx] : i;
        uint4 u = *(const uint4*)(hw1b + (size_t)src * 64 + c * 8);
        float m = v ? 1.f : 0.f;
        acc[0] = fmaf(m, uaf(u.x << 16),         acc[0]);
        acc[1] = fmaf(m, uaf(u.x & 0xffff0000u), acc[1]);
        acc[2] = fmaf(m, uaf(u.y << 16),         acc[2]);
        acc[3] = fmaf(m, uaf(u.y & 0xffff0000u), acc[3]);
        acc[4] = fmaf(m, uaf(u.z << 16),         acc[4]);
        acc[5] = fmaf(m, uaf(u.z & 0xffff0000u), acc[5]);
        acc[6] = fmaf(m, uaf(u.w << 16),         acc[6]);
        acc[7] = fmaf(m, uaf(u.w & 0xffff0000u), acc[7]);
    }
    // butterfly reduce across the 8 edge-slots
    #pragma unroll
    for (int j = 0; j < 8; ++j) {
        acc[j] += __shfl_xor(acc[j], 8, 64);
        acc[j] += __shfl_xor(acc[j], 16, 64);
        acc[j] += __shfl_xor(acc[j], 32, 64);
    }
    // transpose: lane l pulls acc[l&7] from lane (l>>3)  => lane = feature
    int srcl = l >> 3;
    float t0 = __shfl(acc[0], srcl, 64);
    float t1 = __shfl(acc[1], srcl, 64);
    float t2 = __shfl(acc[2], srcl, 64);
    float t3 = __shfl(acc[3], srcl, 64);
    float t4 = __shfl(acc[4], srcl, 64);
    float t5 = __shfl(acc[5], srcl, 64);
    float t6 = __shfl(acc[6], srcl, 64);
    float t7 = __shfl(acc[7], srcl, 64);
    int j = l & 7;
    float v = t0;
    v = (j == 1) ? t1 : v;
    v = (j == 2) ? t2 : v;
    v = (j == 3) ? t3 : v;
    v = (j == 4) ? t4 : v;
    v = (j == 5) ? t5 : v;
    v = (j == 6) ? t6 : v;
    v = (j == 7) ? t7 : v;
    // self-loop + relu + ONE coalesced pooled atomic (lane = feature)
    float self = __bfloat162float(hw1b[(size_t)i * 64 + l]);
    float h2 = fmaxf(fmaf(dis[i], v + self, bg2[l]), 0.f);
    atomicAdd(&pool[(size_t)batch[i] * 64 + l], h2);
}

// per-graph head: tabular MLP + mean pool + fusion MLP. 64 threads per graph.
__global__ void __launch_bounds__(64) k_head(const float* tabular,
        const float* Wt1, const float* bt1, const float* Wt2, const float* bt2,
        const float* Wf1, const float* bf1, const float* Wf2, const float* bf2,
        const float* pool, const int* batch, float* out, int TD, int N) {
    __shared__ float tl[128];
    __shared__ float t1[64];
    __shared__ float comb[128];
    __shared__ float f1[64];
    __shared__ float cnts;
    int g = blockIdx.x, l = threadIdx.x;
    if (l == 0) {
        int lo = 0, hi = N;
        while (lo < hi) { int m = (lo + hi) >> 1; if (batch[m] < g) lo = m + 1; else hi = m; }
        int lo2 = lo, hi2 = N;
        while (lo2 < hi2) { int m = (lo2 + hi2) >> 1; if (batch[m] <= g) lo2 = m + 1; else hi2 = m; }
        int c = lo2 - lo;
        cnts = (float)(c > 1 ? c : 1);
    }
    for (int k = l; k < TD; k += 64) tl[k] = tabular[g * TD + k];
    __syncthreads();
    float a = bt1[l];
    for (int k = 0; k < TD; ++k) a += tl[k] * Wt1[k * 64 + l];
    t1[l] = a > 0.f ? a : 0.f;
    __syncthreads();
    float b = bt2[l];
    #pragma unroll
    for (int k = 0; k < 64; ++k) b += t1[k] * Wt2[k * 64 + l];
    comb[l] = b;
    comb[64 + l] = pool[g * 64 + l] / cnts;
    __syncthreads();
    float f = bf1[l];
    for (int k = 0; k < 128; ++k) f += comb[k] * Wf1[k * 64 + l];
    f1[l] = f > 0.f ? f : 0.f;
    __syncthreads();
    if (l < 2) {
        float o = bf2[l];
        #pragma unroll
        for (int k = 0; k < 64; ++k) o += f1[k] * Wf2[k * 2 + l];
        out[g * 2 + l] = o;
    }
}

// ---------------- launcher ----------------

extern "C" void kernel_launch(void* const* d_in, const int* in_sizes, int n_in,
                              void* d_out, int out_size, void* d_ws, size_t ws_size,
                              hipStream_t stream) {
    const float* tabular = (const float*)d_in[0];
    const float* x       = (const float*)d_in[1];
    const int*   ei      = (const int*)d_in[2];
    const int*   batch   = (const int*)d_in[3];
    const float* Wt1 = (const float*)d_in[4];
    const float* bt1 = (const float*)d_in[5];
    const float* Wt2 = (const float*)d_in[6];
    const float* bt2 = (const float*)d_in[7];
    const float* Wg1 = (const float*)d_in[8];
    const float* bg1 = (const float*)d_in[9];
    const float* Wg2 = (const float*)d_in[10];
    const float* bg2 = (const float*)d_in[11];
    const float* Wf1 = (const float*)d_in[12];
    const float* bf1 = (const float*)d_in[13];
    const float* Wf2 = (const float*)d_in[14];
    const float* bf2 = (const float*)d_in[15];

    const int N  = in_sizes[1];
    const int E  = in_sizes[2] / 2;
    const int H  = in_sizes[5];             // 64
    const int TD = in_sizes[4] / H;         // 128
    const int B  = in_sizes[0] / TD;        // 1024
    const int NB = (N + BK - 1) / BK;       // 1563

    // workspace layout
    char* w = (char*)d_ws;
    size_t off = 0;
    auto alloc = [&](size_t bytes) -> void* {
        void* p = w + off;
        off = (off + bytes + 255) & ~(size_t)255;
        return p;
    };
    int*   bcnt = (int*)alloc((size_t)NBMAX * 4);
    int*   boff = (int*)alloc((size_t)(NBMAX + 1) * 4);
    int*   bcur = (int*)alloc((size_t)NBMAX * 4);
    int*   offs = (int*)alloc((size_t)(N + 1) * 4);
    float* dis  = (float*)alloc((size_t)N * 4);
    float* dx   = (float*)alloc((size_t)N * 4);
    float* s1   = (float*)alloc((size_t)N * 4);
    unsigned* stag = (unsigned*)alloc((size_t)E * 4);
    int*   csr  = (int*)alloc((size_t)E * 4);
    __hip_bfloat16* hw1b = (__hip_bfloat16*)alloc((size_t)N * 64 * 2);
    float* pool = (float*)alloc((size_t)B * 64 * 4);
    (void)ws_size;

    hipMemsetAsync(bcnt, 0, (size_t)NB * 4, stream);
    hipMemsetAsync(pool, 0, (size_t)B * 64 * 4, stream);

    k_bcount<<<512, 256, 0, stream>>>(ei + E, bcnt, E, NB);
    k_bscan<<<1, 256, 0, stream>>>(bcnt, boff, bcur, NB, E);
    k_bscatter<<<(E + EPB - 1) / EPB, 256, 0, stream>>>(ei, bcur, stag, E, NB);
    k_sort<<<NB, 256, 0, stream>>>(boff, stag, x, csr, offs, dis, dx, N, NB);
    k_agg1<<<(N + 255) / 256, 256, 0, stream>>>(offs, csr, dx, dis, s1, N);
    k_hw1<<<(N + 15) / 16, 256, 0, stream>>>(s1, dis, Wg1, bg1, Wg2, hw1b, N);
    k_agg2<<<(N + 3) / 4, 256, 0, stream>>>(offs, csr, hw1b, dis, bg2, batch, pool, N);
    k_head<<<B, 64, 0, stream>>>(tabular, Wt1, bt1, Wt2, bt2,
                                 Wf1, bf1, Wf2, bf2, pool, batch,
                                 (float*)d_out, TD, N);
}

// Round 10
// 568.962 us; speedup vs baseline: 1.8268x; 1.0280x over previous
//
#include <hip/hip_runtime.h>
#include <hip/hip_bf16.h>

#define BK    512     // nodes per bucket
#define BKSH  9       // log2(BK)
#define NBMAX 512     // max buckets (N <= 262144)

__device__ __forceinline__ float uaf(unsigned u) { return __uint_as_float(u); }

__device__ __forceinline__ void acc8(float* acc, uint4 u) {
    acc[0] += uaf(u.x << 16); acc[1] += uaf(u.x & 0xffff0000u);
    acc[2] += uaf(u.y << 16); acc[3] += uaf(u.y & 0xffff0000u);
    acc[4] += uaf(u.z << 16); acc[5] += uaf(u.z & 0xffff0000u);
    acc[6] += uaf(u.w << 16); acc[7] += uaf(u.w & 0xffff0000u);
}

// ---------------- bucket-grouped edge staging ----------------

// count edges per bucket (bucket = dst >> BKSH)
__global__ void __launch_bounds__(256) k_bcount(const int* dst, int* bcnt, int E, int NB) {
    __shared__ int h[NBMAX];
    for (int i = threadIdx.x; i < NB; i += 256) h[i] = 0;
    __syncthreads();
    int stride = gridDim.x * 256;
    for (int e = blockIdx.x * 256 + threadIdx.x; e < E; e += stride)
        atomicAdd(&h[dst[e] >> BKSH], 1);
    __syncthreads();
    for (int i = threadIdx.x; i < NB; i += 256) {
        int v = h[i];
        if (v) atomicAdd(&bcnt[i], v);
    }
}

// exclusive scan of bucket counts (single block, loops over 256-chunks)
__global__ void __launch_bounds__(256) k_bscan(const int* bcnt, int* boff, int* bcur, int NB, int E) {
    __shared__ int lds[256];
    __shared__ int carry;
    int t = threadIdx.x;
    if (t == 0) carry = 0;
    __syncthreads();
    for (int base = 0; base < NB; base += 256) {
        int v = (base + t < NB) ? bcnt[base + t] : 0;
        lds[t] = v;
        __syncthreads();
        for (int o = 1; o < 256; o <<= 1) {
            int u = (t >= o) ? lds[t - o] : 0;
            __syncthreads();
            lds[t] += u;
            __syncthreads();
        }
        int excl = lds[t] - v + carry;
        if (base + t < NB) { boff[base + t] = excl; bcur[base + t] = excl; }
        __syncthreads();
        if (t == 0) carry += lds[255];
        __syncthreads();
    }
    if (t == 0) boff[NB] = E;
}

// scatter packed (src<<BKSH | dst&(BK-1)) into bucket-grouped staging.
#define EPB 16384
__global__ void __launch_bounds__(256) k_bscatter(const int* ei, int* bcur,
                                                  unsigned* stag, int E, int NB) {
    __shared__ int lhist[NBMAX];
    __shared__ int lbase[NBMAX];
    int t = threadIdx.x;
    for (int i = t; i < NB; i += 256) lhist[i] = 0;
    __syncthreads();
    int base = blockIdx.x * EPB;
    int lim = min(EPB, E - base);
    for (int c = t; c < lim; c += 256)
        atomicAdd(&lhist[ei[E + base + c] >> BKSH], 1);
    __syncthreads();
    for (int i = t; i < NB; i += 256) {
        int v = lhist[i];
        lbase[i] = v ? atomicAdd(&bcur[i], v) : 0;
    }
    __syncthreads();
    for (int c = t; c < lim; c += 256) {
        int s = ei[base + c];
        int d = ei[E + base + c];
        int p = atomicAdd(&lbase[d >> BKSH], 1);
        stag[p] = ((unsigned)s << BKSH) | (unsigned)(d & (BK - 1));
    }
}

// per-bucket counting sort: stag (bucket-grouped) -> csr (node-grouped).
// 512 bins scanned pair-per-thread by 256 threads. Emits offs, dis, dx.
__global__ void __launch_bounds__(256) k_sort(const int* boff, const unsigned* stag,
                                              const float* x, int* csr, int* offs,
                                              float* dis, float* dx, int N, int NB) {
    __shared__ int cnt[BK];
    __shared__ int lds[256];
    __shared__ int base[BK];
    int t = threadIdx.x, bu = blockIdx.x;
    cnt[t] = 0; cnt[t + 256] = 0;
    __syncthreads();
    int lo = boff[bu], hi = boff[bu + 1];
    for (int k = lo + t; k < hi; k += 256)
        atomicAdd(&cnt[stag[k] & (BK - 1)], 1);
    __syncthreads();
    int v0 = cnt[2 * t], v1 = cnt[2 * t + 1];
    int s = v0 + v1;
    lds[t] = s;
    __syncthreads();
    for (int o = 1; o < 256; o <<= 1) {
        int u = (t >= o) ? lds[t - o] : 0;
        __syncthreads();
        lds[t] += u;
        __syncthreads();
    }
    int excl = lds[t] - s;
    base[2 * t] = excl;
    base[2 * t + 1] = excl + v0;
    int node0 = bu * BK + 2 * t;
    int node1 = node0 + 1;
    if (node0 < N) {
        offs[node0] = lo + excl;
        float d = rsqrtf((float)(v0 + 1));   // +1 self-loop
        dis[node0] = d;
        dx[node0]  = d * x[node0];
    }
    if (node1 < N) {
        offs[node1] = lo + excl + v0;
        float d = rsqrtf((float)(v1 + 1));
        dis[node1] = d;
        dx[node1]  = d * x[node1];
    }
    if (bu == NB - 1 && t == 0) offs[N] = hi;
    __syncthreads();
    for (int k = lo + t; k < hi; k += 256) {
        unsigned en = stag[k];
        int p = atomicAdd(&base[en & (BK - 1)], 1);
        csr[lo + p] = (int)(en >> BKSH);
    }
}

// layer-1 scalar aggregation: thread per node on sorted CSR (self-loop analytic)
__global__ void k_agg1(const int* offs, const int* csr, const float* dx,
                       const float* dis, float* s1, int N) {
    int i = blockIdx.x * blockDim.x + threadIdx.x;
    if (i >= N) return;
    int b = offs[i], e = offs[i + 1];
    float acc = 0.f;
    int k = b;
    for (; k + 8 <= e; k += 8) {
        int s0 = csr[k], s1_ = csr[k + 1], s2 = csr[k + 2], s3 = csr[k + 3];
        int s4 = csr[k + 4], s5 = csr[k + 5], s6 = csr[k + 6], s7 = csr[k + 7];
        float v0 = dx[s0], v1 = dx[s1_], v2 = dx[s2], v3 = dx[s3];
        float v4 = dx[s4], v5 = dx[s5], v6 = dx[s6], v7 = dx[s7];
        acc += ((v0 + v1) + (v2 + v3)) + ((v4 + v5) + (v6 + v7));
    }
    for (; k < e; ++k) acc += dx[csr[k]];
    s1[i] = dis[i] * (acc + dx[i]);
}

// hw1b[i] = bf16( dis[i] * (relu(s1[i]*Wg1 + bg1) @ Wg2) ), Wg2 in LDS
__global__ void __launch_bounds__(256) k_hw1(const float* s1, const float* dis,
                                             const float* Wg1, const float* bg1,
                                             const float* Wg2,
                                             __hip_bfloat16* hw1b, int N) {
    __shared__ float w2[64 * 64];
    __shared__ float h1l[4][64];
    int t = threadIdx.x;
    for (int k = t; k < 64 * 64; k += 256) w2[k] = Wg2[k];
    int nl = t >> 6, l = t & 63;
    int base = blockIdx.x * 16;
    for (int g = 0; g < 4; ++g) {
        int node = base + g * 4 + nl;
        float h1 = 0.f;
        if (node < N)
            h1 = fmaxf(fmaf(s1[node], Wg1[l], bg1[l]), 0.f);
        __syncthreads();
        h1l[nl][l] = h1;
        __syncthreads();
        if (node < N) {
            float acc = 0.f;
            const float* hr = h1l[nl];
            #pragma unroll
            for (int k = 0; k < 64; ++k) acc += hr[k] * w2[k * 64 + l];
            hw1b[node * 64 + l] = __float2bfloat16(dis[node] * acc);
        }
    }
}

// layer-2 aggregation: wave per dst node; 8 edge-slots x 8 feature-chunks.
// Lane l: edge k+(l>>3), features (l&7)*8..+7 via one uint4 (16B = 8 bf16).
// 4x unrolled = 64 lines in flight per wave. Finalize: butterfly over slots,
// 8-shuffle transpose back to lane=feature, ONE coalesced 64-lane atomic.
__global__ void __launch_bounds__(256) k_agg2(const int* offs, const int* csr,
                                              const __hip_bfloat16* hw1b,
                                              const float* dis, const float* bg2,
                                              const int* batch, float* pool, int N) {
    int i = (blockIdx.x * 256 + threadIdx.x) >> 6;  // node = global wave id
    if (i >= N) return;
    int l = threadIdx.x & 63;
    int slot = l >> 3;          // which of 8 edges
    int c    = l & 7;           // feature chunk: features c*8 .. c*8+7
    int b = offs[i], e = offs[i + 1];
    float acc[8] = {0.f, 0.f, 0.f, 0.f, 0.f, 0.f, 0.f, 0.f};
    int k = b;
    for (; k + 32 <= e; k += 32) {
        int sA = csr[k + slot];
        int sB = csr[k + 8 + slot];
        int sC = csr[k + 16 + slot];
        int sD = csr[k + 24 + slot];
        uint4 uA = *(const uint4*)(hw1b + (size_t)sA * 64 + c * 8);
        uint4 uB = *(const uint4*)(hw1b + (size_t)sB * 64 + c * 8);
        uint4 uC = *(const uint4*)(hw1b + (size_t)sC * 64 + c * 8);
        uint4 uD = *(const uint4*)(hw1b + (size_t)sD * 64 + c * 8);
        acc8(acc, uA); acc8(acc, uB); acc8(acc, uC); acc8(acc, uD);
    }
    for (; k + 16 <= e; k += 16) {
        int sA = csr[k + slot];
        int sB = csr[k + 8 + slot];
        uint4 uA = *(const uint4*)(hw1b + (size_t)sA * 64 + c * 8);
        uint4 uB = *(const uint4*)(hw1b + (size_t)sB * 64 + c * 8);
        acc8(acc, uA); acc8(acc, uB);
    }
    for (; k + 8 <= e; k += 8) {
        int sA = csr[k + slot];
        uint4 uA = *(const uint4*)(hw1b + (size_t)sA * 64 + c * 8);
        acc8(acc, uA);
    }
    if (k < e) {   // masked tail, <8 edges
        int idx = k + slot;
        bool v = idx < e;
        int src = v ? csr[idx] : i;
        uint4 u = *(const uint4*)(hw1b + (size_t)src * 64 + c * 8);
        float m = v ? 1.f : 0.f;
        acc[0] = fmaf(m, uaf(u.x << 16),         acc[0]);
        acc[1] = fmaf(m, uaf(u.x & 0xffff0000u), acc[1]);
        acc[2] = fmaf(m, uaf(u.y << 16),         acc[2]);
        acc[3] = fmaf(m, uaf(u.y & 0xffff0000u), acc[3]);
        acc[4] = fmaf(m, uaf(u.z << 16),         acc[4]);
        acc[5] = fmaf(m, uaf(u.z & 0xffff0000u), acc[5]);
        acc[6] = fmaf(m, uaf(u.w << 16),         acc[6]);
        acc[7] = fmaf(m, uaf(u.w & 0xffff0000u), acc[7]);
    }
    // butterfly reduce across the 8 edge-slots
    #pragma unroll
    for (int j = 0; j < 8; ++j) {
        acc[j] += __shfl_xor(acc[j], 8, 64);
        acc[j] += __shfl_xor(acc[j], 16, 64);
        acc[j] += __shfl_xor(acc[j], 32, 64);
    }
    // transpose: lane l pulls acc[l&7] from lane (l>>3)  => lane = feature
    int srcl = l >> 3;
    float t0 = __shfl(acc[0], srcl, 64);
    float t1 = __shfl(acc[1], srcl, 64);
    float t2 = __shfl(acc[2], srcl, 64);
    float t3 = __shfl(acc[3], srcl, 64);
    float t4 = __shfl(acc[4], srcl, 64);
    float t5 = __shfl(acc[5], srcl, 64);
    float t6 = __shfl(acc[6], srcl, 64);
    float t7 = __shfl(acc[7], srcl, 64);
    int j = l & 7;
    float v = t0;
    v = (j == 1) ? t1 : v;
    v = (j == 2) ? t2 : v;
    v = (j == 3) ? t3 : v;
    v = (j == 4) ? t4 : v;
    v = (j == 5) ? t5 : v;
    v = (j == 6) ? t6 : v;
    v = (j == 7) ? t7 : v;
    // self-loop + relu + ONE coalesced pooled atomic (lane = feature)
    float self = __bfloat162float(hw1b[(size_t)i * 64 + l]);
    float h2 = fmaxf(fmaf(dis[i], v + self, bg2[l]), 0.f);
    atomicAdd(&pool[(size_t)batch[i] * 64 + l], h2);
}

// per-graph head: tabular MLP + mean pool + fusion MLP. 64 threads per graph.
__global__ void __launch_bounds__(64) k_head(const float* tabular,
        const float* Wt1, const float* bt1, const float* Wt2, const float* bt2,
        const float* Wf1, const float* bf1, const float* Wf2, const float* bf2,
        const float* pool, const int* batch, float* out, int TD, int N) {
    __shared__ float tl[128];
    __shared__ float t1[64];
    __shared__ float comb[128];
    __shared__ float f1[64];
    __shared__ float cnts;
    int g = blockIdx.x, l = threadIdx.x;
    if (l == 0) {
        int lo = 0, hi = N;
        while (lo < hi) { int m = (lo + hi) >> 1; if (batch[m] < g) lo = m + 1; else hi = m; }
        int lo2 = lo, hi2 = N;
        while (lo2 < hi2) { int m = (lo2 + hi2) >> 1; if (batch[m] <= g) lo2 = m + 1; else hi2 = m; }
        int c = lo2 - lo;
        cnts = (float)(c > 1 ? c : 1);
    }
    for (int k = l; k < TD; k += 64) tl[k] = tabular[g * TD + k];
    __syncthreads();
    float a = bt1[l];
    for (int k = 0; k < TD; ++k) a += tl[k] * Wt1[k * 64 + l];
    t1[l] = a > 0.f ? a : 0.f;
    __syncthreads();
    float b = bt2[l];
    #pragma unroll
    for (int k = 0; k < 64; ++k) b += t1[k] * Wt2[k * 64 + l];
    comb[l] = b;
    comb[64 + l] = pool[g * 64 + l] / cnts;
    __syncthreads();
    float f = bf1[l];
    for (int k = 0; k < 128; ++k) f += comb[k] * Wf1[k * 64 + l];
    f1[l] = f > 0.f ? f : 0.f;
    __syncthreads();
    if (l < 2) {
        float o = bf2[l];
        #pragma unroll
        for (int k = 0; k < 64; ++k) o += f1[k] * Wf2[k * 2 + l];
        out[g * 2 + l] = o;
    }
}

// ---------------- launcher ----------------

extern "C" void kernel_launch(void* const* d_in, const int* in_sizes, int n_in,
                              void* d_out, int out_size, void* d_ws, size_t ws_size,
                              hipStream_t stream) {
    const float* tabular = (const float*)d_in[0];
    const float* x       = (const float*)d_in[1];
    const int*   ei      = (const int*)d_in[2];
    const int*   batch   = (const int*)d_in[3];
    const float* Wt1 = (const float*)d_in[4];
    const float* bt1 = (const float*)d_in[5];
    const float* Wt2 = (const float*)d_in[6];
    const float* bt2 = (const float*)d_in[7];
    const float* Wg1 = (const float*)d_in[8];
    const float* bg1 = (const float*)d_in[9];
    const float* Wg2 = (const float*)d_in[10];
    const float* bg2 = (const float*)d_in[11];
    const float* Wf1 = (const float*)d_in[12];
    const float* bf1 = (const float*)d_in[13];
    const float* Wf2 = (const float*)d_in[14];
    const float* bf2 = (const float*)d_in[15];

    const int N  = in_sizes[1];
    const int E  = in_sizes[2] / 2;
    const int H  = in_sizes[5];             // 64
    const int TD = in_sizes[4] / H;         // 128
    const int B  = in_sizes[0] / TD;        // 1024
    const int NB = (N + BK - 1) / BK;       // 391

    // workspace layout
    char* w = (char*)d_ws;
    size_t off = 0;
    auto alloc = [&](size_t bytes) -> void* {
        void* p = w + off;
        off = (off + bytes + 255) & ~(size_t)255;
        return p;
    };
    int*   bcnt = (int*)alloc((size_t)NBMAX * 4);
    int*   boff = (int*)alloc((size_t)(NBMAX + 1) * 4);
    int*   bcur = (int*)alloc((size_t)NBMAX * 4);
    int*   offs = (int*)alloc((size_t)(N + 1) * 4);
    float* dis  = (float*)alloc((size_t)N * 4);
    float* dx   = (float*)alloc((size_t)N * 4);
    float* s1   = (float*)alloc((size_t)N * 4);
    unsigned* stag = (unsigned*)alloc((size_t)E * 4);
    int*   csr  = (int*)alloc((size_t)E * 4);
    __hip_bfloat16* hw1b = (__hip_bfloat16*)alloc((size_t)N * 64 * 2);
    float* pool = (float*)alloc((size_t)B * 64 * 4);
    (void)ws_size;

    hipMemsetAsync(bcnt, 0, (size_t)NB * 4, stream);
    hipMemsetAsync(pool, 0, (size_t)B * 64 * 4, stream);

    k_bcount<<<512, 256, 0, stream>>>(ei + E, bcnt, E, NB);
    k_bscan<<<1, 256, 0, stream>>>(bcnt, boff, bcur, NB, E);
    k_bscatter<<<(E + EPB - 1) / EPB, 256, 0, stream>>>(ei, bcur, stag, E, NB);
    k_sort<<<NB, 256, 0, stream>>>(boff, stag, x, csr, offs, dis, dx, N, NB);
    k_agg1<<<(N + 255) / 256, 256, 0, stream>>>(offs, csr, dx, dis, s1, N);
    k_hw1<<<(N + 15) / 16, 256, 0, stream>>>(s1, dis, Wg1, bg1, Wg2, hw1b, N);
    k_agg2<<<(N + 3) / 4, 256, 0, stream>>>(offs, csr, hw1b, dis, bg2, batch, pool, N);
    k_head<<<B, 64, 0, stream>>>(tabular, Wt1, bt1, Wt2, bt2,
                                 Wf1, bf1, Wf2, bf2, pool, batch,
                                 (float*)d_out, TD, N);
}